// Round 7
// baseline (568.306 us; speedup 1.0000x reference)
//
#include <hip/hip_runtime.h>
#include <stdint.h>

// B=4, C=192, H=W=224, WS=8, NH=6, hd=32, SHIFT=4. I/O fp32; internal bf16 MFMA.
#define HHW   224
#define CCH   192
#define SHIFT 4
#define NWIN  3136           // 4 * 28 * 28
#define NTOK  200704         // NWIN * 64
#define QN    38535168ull    // NWIN*64*192 elements (bf16) = 77 MB region

typedef __attribute__((ext_vector_type(8))) short bf16x8;   // MFMA A/B frag
typedef __attribute__((ext_vector_type(4))) float f32x4;    // MFMA C/D frag

__device__ __forceinline__ ushort f2bf(float f) {
    union { float f; uint32_t i; } v; v.f = f;
    uint32_t u = v.i;
    return (ushort)((u + 0x7FFFu + ((u >> 16) & 1u)) >> 16);  // RNE
}
__device__ __forceinline__ uint32_t pk2(float a, float b) {
    return (uint32_t)f2bf(a) | ((uint32_t)f2bf(b) << 16);
}
#define GLOAD16(src, dst) __builtin_amdgcn_global_load_lds( \
    (const __attribute__((address_space(1))) void*)(src),   \
    (__attribute__((address_space(3))) void*)(dst), 16, 0, 0)

// ---------------------------------------------------------------------------
// prep_w_qkv: w_qkv fp32 [576][192] -> bf16 SLICE-sequential image.
// slice s = chunk*6 + k (36 slices x 6144B); within slice: [quad][m][l16][8].
// Chunk mapping: Q rows are HEAD-MAJOR (chunk 0: m=head, li=ch 0-15; chunk 1:
// ch 16-31) so gemm wave w accumulates head w's full Q in registers.
// K: chunks 2,3 (m = 16-row groups); V: chunks 4,5.
// ---------------------------------------------------------------------------
__global__ __launch_bounds__(256) void prep_w_qkv(const float* __restrict__ w,
                                                  ushort* __restrict__ wo)
{
    int idx = blockIdx.x * 256 + threadIdx.x;
    if (idx >= 576 * 24) return;
    int rg = idx / 24, p = idx % 24;
    int s3 = rg / 192, r = rg % 192;
    int chunk, m;
    if (s3 == 0) { chunk = (r & 31) >> 4; m = r >> 5; }
    else         { chunk = 2 * s3 + (r >= 96); m = (r % 96) >> 4; }
    int li = r & 15;
    int k = p >> 2, quad = p & 3;
    int slice = chunk * 6 + k;
    const float* src = w + (size_t)rg * 192 + p * 8;
    float4 a = *(const float4*)src;
    float4 b = *(const float4*)(src + 4);
    uint4 o;
    o.x = pk2(a.x, a.y); o.y = pk2(a.z, a.w);
    o.z = pk2(b.x, b.y); o.w = pk2(b.z, b.w);
    *(uint4*)(wo + ((size_t)slice * 384 + (quad * 6 + m) * 16 + li) * 8) = o;
}

// ---------------------------------------------------------------------------
// prep_w_proj: w_proj fp32 [192][192] -> bf16 fragment image [k][quad][m12][l16][8]
// staged whole (73.7KB) by gemm_proj.
// ---------------------------------------------------------------------------
__global__ __launch_bounds__(256) void prep_w_proj(const float* __restrict__ w,
                                                   ushort* __restrict__ wo)
{
    int idx = blockIdx.x * 256 + threadIdx.x;
    if (idx >= 192 * 24) return;
    int rg = idx / 24, p = idx % 24;
    int k = p >> 2, quad = p & 3;
    const float* src = w + (size_t)rg * 192 + p * 8;
    float4 a = *(const float4*)src;
    float4 b = *(const float4*)(src + 4);
    uint4 o;
    o.x = pk2(a.x, a.y); o.y = pk2(a.z, a.w);
    o.z = pk2(b.x, b.y); o.w = pk2(b.z, b.w);
    *(uint4*)(wo + ((((size_t)(k * 4 + quad) * 12 + (rg >> 4)) * 16 + (rg & 15))) * 8) = o;
}

// ---------------------------------------------------------------------------
// prep_x: x fp32 [b][c][h][w] -> X1 bf16 [win][oct][t][8ch], roll(+4) folded.
// Full-row reads (zero over-fetch); swizzled LDS transpose; 1KB output bursts.
// ---------------------------------------------------------------------------
__global__ __launch_bounds__(256) void prep_x(const float* __restrict__ x,
                                              ushort* __restrict__ xo)
{
    __shared__ ushort lt[1792 * 8];
    const int blk = blockIdx.x;
    const int oct = blk % 24;
    const int bh  = blk / 24;
    const int hn  = bh % 28;
    const float* xb = x + ((size_t)(bh / 28) * CCH + oct * 8) * (HHW * HHW);

    for (int u = threadIdx.x; u < 448; u += 256) {
        int r = u / 56, q = u % 56;
        int hh = (hn * 8 + r + SHIFT) % HHW;
        int ww = (q * 4 + SHIFT) % HHW;
        const float* src = xb + (size_t)hh * HHW + ww;
        float4 v[8];
        #pragma unroll
        for (int c = 0; c < 8; c++)
            v[c] = *(const float4*)(src + (size_t)c * (HHW * HHW));
        #pragma unroll
        for (int i = 0; i < 4; i++) {
            int p = u * 4 + i;
            int sw = p ^ ((p >> 3) & 7);
            uint4 o;
            o.x = pk2(((const float*)&v[0])[i], ((const float*)&v[1])[i]);
            o.y = pk2(((const float*)&v[2])[i], ((const float*)&v[3])[i]);
            o.z = pk2(((const float*)&v[4])[i], ((const float*)&v[5])[i]);
            o.w = pk2(((const float*)&v[6])[i], ((const float*)&v[7])[i]);
            *(uint4*)&lt[sw * 8] = o;
        }
    }
    __syncthreads();

    for (int u = threadIdx.x; u < 1792; u += 256) {
        int wn = u >> 6, t = u & 63;
        int p = (t >> 3) * 224 + wn * 8 + (t & 7);
        int sw = p ^ ((p >> 3) & 7);
        *(uint4*)(xo + (size_t)(bh * 28 + wn) * 12288 + oct * 512 + t * 8) =
            *(const uint4*)&lt[sw * 8];
    }
}

// ---------------------------------------------------------------------------
// qkv_attn_win v2: fused qkv-gemm + attention, 2 blocks/CU (LDS 79872B).
// 6 waves; weight pipeline = 18 phases x 12KB dbuf (2 k-slices/phase).
// Q stays IN REGISTERS (head-major weight permutation: wave w = head w);
// K->LDS [h][t][d] pitch 72B (36 ushorts); V->LDS [h][d][t] pitch 144B.
// Attn: kf/vf hoisted to regs, barrier, then P-tiles alias dead W+K LDS.
// qf built from Q-acc via 8 shfl+4 select per tile (D->B lane transpose).
// ---------------------------------------------------------------------------
__global__ __launch_bounds__(384, 3) void qkv_attn_win(
    const ushort* __restrict__ xin,   // X1 [win][oct][t][8]
    const ushort* __restrict__ wbf,   // slice-sequential qkv weight image
    const float* __restrict__ bias,   // b_qkv
    ushort* __restrict__ x2o)         // X2 [win*64+t][192]
{
    // [0,24576) W dbuf 2x12288 | [24576,52224) K 6h x 64t x 72B
    // [52224,79872) V 6h x 32d x 144B | P aliases [0,49152) in attn phase
    __shared__ __align__(16) char smem[79872];
    ushort* const kl = (ushort*)(smem + 24576);
    ushort* const vl = (ushort*)(smem + 52224);

    const int tid = threadIdx.x;
    const int wave = tid / 64, lane = tid & 63;
    const int quad = lane >> 4, l16 = lane & 15;
    const int win = blockIdx.x;
    const ushort* xw = xin + (size_t)win * 12288;

    // prologue: stage phase 0 (slices 0,1)
    {
        const ushort* src = wbf + wave * 512 + lane * 8;
        GLOAD16(src, smem + wave * 1024);
        GLOAD16(src + 3072, smem + 6144 + wave * 1024);
    }
    __syncthreads();

    uint32_t pq0[4][2], pq1[4][2];   // head-w Q, packed bf16 pairs (ck 0/1)

    #pragma unroll
    for (int ch = 0; ch < 6; ch++) {
        f32x4 a[4];
        #pragma unroll
        for (int nt = 0; nt < 4; nt++) a[nt] = (f32x4){0.f, 0.f, 0.f, 0.f};
        #pragma unroll
        for (int ph3 = 0; ph3 < 3; ph3++) {
            const int p = ch * 3 + ph3;
            if (p < 17) {
                const ushort* src = wbf + (size_t)(p + 1) * 6144 + wave * 512 + lane * 8;
                char* db = smem + ((p + 1) & 1) * 12288 + wave * 1024;
                GLOAD16(src, db);
                GLOAD16(src + 3072, db + 6144);
            }
            const ushort* cb = (const ushort*)(smem + (p & 1) * 12288);
            #pragma unroll
            for (int sl = 0; sl < 2; sl++) {
                const int k = ph3 * 2 + sl;
                bf16x8 bq[4];
                #pragma unroll
                for (int nt = 0; nt < 4; nt++)
                    bq[nt] = *(const bf16x8*)(xw + (k * 4 + quad) * 512 + (nt * 16 + l16) * 8);
                bf16x8 af = *(const bf16x8*)(cb + sl * 3072 + ((quad * 6 + wave) * 16 + l16) * 8);
                #pragma unroll
                for (int nt = 0; nt < 4; nt++)
                    a[nt] = __builtin_amdgcn_mfma_f32_16x16x32_bf16(af, bq[nt], a[nt], 0, 0, 0);
            }
            if (ph3 == 2) {
                // chunk epilogue
                if (ch < 2) {               // Q -> registers, packed
                    float4 bb = *(const float4*)(bias + wave * 32 + ch * 16 + quad * 4);
                    #pragma unroll
                    for (int nt = 0; nt < 4; nt++) {
                        uint32_t lo = pk2(a[nt][0] + bb.x, a[nt][1] + bb.y);
                        uint32_t hi = pk2(a[nt][2] + bb.z, a[nt][3] + bb.w);
                        if (ch == 0) { pq0[nt][0] = lo; pq0[nt][1] = hi; }
                        else         { pq1[nt][0] = lo; pq1[nt][1] = hi; }
                    }
                } else if (ch < 4) {        // K -> LDS [h][t][d] pitch 36 ushorts
                    float4 bb = *(const float4*)(bias + 192 + (ch - 2) * 96 + wave * 16 + quad * 4);
                    const int hk = (ch - 2) * 3 + (wave >> 1);
                    const int d0 = (wave & 1) * 16 + quad * 4;
                    #pragma unroll
                    for (int nt = 0; nt < 4; nt++) {
                        const int t = nt * 16 + l16;
                        uint2 w;
                        w.x = pk2(a[nt][0] + bb.x, a[nt][1] + bb.y);
                        w.y = pk2(a[nt][2] + bb.z, a[nt][3] + bb.w);
                        *(uint2*)(kl + hk * 2304 + t * 36 + d0) = w;
                    }
                } else {                    // V -> LDS [h][d][t] pitch 72 ushorts
                    float4 bb = *(const float4*)(bias + 384 + (ch - 4) * 96 + wave * 16 + quad * 4);
                    const int hv = (ch - 4) * 3 + (wave >> 1);
                    const int d0 = (wave & 1) * 16 + quad * 4;
                    ushort* vh = vl + hv * 2304;
                    #pragma unroll
                    for (int nt = 0; nt < 4; nt++) {
                        const int t = nt * 16 + l16;
                        vh[(d0 + 0) * 72 + t] = f2bf(a[nt][0] + bb.x);
                        vh[(d0 + 1) * 72 + t] = f2bf(a[nt][1] + bb.y);
                        vh[(d0 + 2) * 72 + t] = f2bf(a[nt][2] + bb.z);
                        vh[(d0 + 3) * 72 + t] = f2bf(a[nt][3] + bb.w);
                    }
                }
            }
            __syncthreads();    // staging drained; next-phase buffer ready
        }
    }

    // ---- attention: wave = head ----
    const int h = wave;
    bf16x8 kf[4], vf[2][2];
    #pragma unroll
    for (int mk = 0; mk < 4; mk++)
        kf[mk] = *(const bf16x8*)(kl + h * 2304 + (mk * 16 + l16) * 36 + quad * 8);
    #pragma unroll
    for (int md = 0; md < 2; md++)
        #pragma unroll
        for (int ks = 0; ks < 2; ks++)
            vf[md][ks] = *(const bf16x8*)(vl + h * 2304 + (md * 16 + l16) * 72 + ks * 32 + quad * 8);
    __syncthreads();   // all K/V reads done before P overwrites [0,49152)

    const float SC = 0.25506953149031837f;   // (1/sqrt(32)) * log2(e)
    ushort* ph = (ushort*)smem + h * 4096;   // P tile: aliases dead W+K LDS
    const int sl0 = ((quad & 1) << 5) + l16; // src lane quad' = 2*(q&1)
    const int sl1 = sl0 + 16;
    const bool hiq = quad >= 2;              // ck = q>>1

    #pragma unroll
    for (int nq = 0; nq < 4; nq += 2) {
        f32x4 sc[2][4];
        #pragma unroll
        for (int j = 0; j < 2; j++) {
            const int nt = nq + j;
            // build qf[nt]: D-layout acc -> B-frag via shfl + select
            uint32_t pa0 = pq0[nt][0], pa1 = pq1[nt][0];
            uint32_t pb0 = pq0[nt][1], pb1 = pq1[nt][1];
            uint32_t t0a = __shfl((int)pa0, sl0), t0b = __shfl((int)pa1, sl0);
            uint32_t t1a = __shfl((int)pb0, sl0), t1b = __shfl((int)pb1, sl0);
            uint32_t t2a = __shfl((int)pa0, sl1), t2b = __shfl((int)pa1, sl1);
            uint32_t t3a = __shfl((int)pb0, sl1), t3b = __shfl((int)pb1, sl1);
            uint4 u;
            u.x = hiq ? t0b : t0a; u.y = hiq ? t1b : t1a;
            u.z = hiq ? t2b : t2a; u.w = hiq ? t3b : t3a;
            bf16x8 qf = *(const bf16x8*)&u;
            #pragma unroll
            for (int mk = 0; mk < 4; mk++) {
                sc[j][mk] = (f32x4){0.f, 0.f, 0.f, 0.f};
                sc[j][mk] = __builtin_amdgcn_mfma_f32_16x16x32_bf16(kf[mk], qf, sc[j][mk], 0, 0, 0);
            }
        }
        #pragma unroll
        for (int j = 0; j < 2; j++) {
            float mx = sc[j][0][0];
            #pragma unroll
            for (int mk = 0; mk < 4; mk++)
                #pragma unroll
                for (int rg = 0; rg < 4; rg++) mx = fmaxf(mx, sc[j][mk][rg]);
            mx = fmaxf(mx, __shfl_xor(mx, 16, 64));
            mx = fmaxf(mx, __shfl_xor(mx, 32, 64));
            float e[4][4];
            float sm = 0.f;
            #pragma unroll
            for (int mk = 0; mk < 4; mk++)
                #pragma unroll
                for (int rg = 0; rg < 4; rg++) {
                    e[mk][rg] = exp2f((sc[j][mk][rg] - mx) * SC);
                    sm += e[mk][rg];
                }
            sm += __shfl_xor(sm, 16, 64);
            sm += __shfl_xor(sm, 32, 64);
            float r = __builtin_amdgcn_rcpf(sm);
            const int q = (nq + j) * 16 + l16;
            const int sx = q & 7;
            ushort* row = ph + q * 64;
            #pragma unroll
            for (int mk = 0; mk < 4; mk++) {
                uint2 w;
                w.x = pk2(e[mk][0] * r, e[mk][1] * r);
                w.y = pk2(e[mk][2] * r, e[mk][3] * r);
                int s0 = mk * 2 + (quad >> 1);
                *(uint2*)(row + (((s0 ^ sx) << 3) + (quad & 1) * 4)) = w;
            }
        }
    }
    // P written & read by the same wave only -> no barrier needed.

    f32x4 o[2][4];
    #pragma unroll
    for (int md = 0; md < 2; md++)
        #pragma unroll
        for (int nq = 0; nq < 4; nq++) o[md][nq] = (f32x4){0.f, 0.f, 0.f, 0.f};
    #pragma unroll
    for (int ks = 0; ks < 2; ks++)
        #pragma unroll
        for (int nq = 0; nq < 4; nq++) {
            const int q = nq * 16 + l16;
            bf16x8 pf = *(const bf16x8*)(ph + q * 64 + ((((ks * 4 + quad) ^ (q & 7))) << 3));
            #pragma unroll
            for (int md = 0; md < 2; md++)
                o[md][nq] = __builtin_amdgcn_mfma_f32_16x16x32_bf16(vf[md][ks], pf, o[md][nq], 0, 0, 0);
        }

    // X2[t][c] bf16: packed 8B stores.
    ushort* x2 = x2o + (size_t)win * 12288;
    #pragma unroll
    for (int md = 0; md < 2; md++)
        #pragma unroll
        for (int nq = 0; nq < 4; nq++) {
            const int q = nq * 16 + l16;
            const int c = h * 32 + md * 16 + quad * 4;
            uint2 w;
            w.x = pk2(o[md][nq][0], o[md][nq][1]);
            w.y = pk2(o[md][nq][2], o[md][nq][3]);
            *(uint2*)(x2 + q * CCH + c) = w;
        }
}

// ---------------------------------------------------------------------------
// gemm_proj v2: out = X2 @ Wproj + b. Block = output ROW-STRIP (b, hn, r):
// N = 224 consecutive pixels of one image row -> every fp32 store is 16
// consecutive addresses (perfect 64B lines). Full 192x192 W staged once in
// LDS (73.7KB, 2 blocks/CU); ZERO barriers after the stage.
// ---------------------------------------------------------------------------
__global__ __launch_bounds__(384, 3) void gemm_proj(
    const ushort* __restrict__ x2, const ushort* __restrict__ wbf,
    const float* __restrict__ bias, float* __restrict__ dout)
{
    __shared__ __align__(16) ushort wl[36864];   // 73728 B

    const int tid = threadIdx.x;
    const int wave = tid / 64, lane = tid & 63;
    const int quad = lane >> 4, l16 = lane & 15;
    const int r  = blockIdx.x & 7;
    const int bh = blockIdx.x >> 3;          // b*28 + hn
    const int b = bh / 28, hn = bh % 28;

    #pragma unroll
    for (int it = 0; it < 12; it++) {
        const ushort* src = wbf + it * 3072 + wave * 512 + lane * 8;
        GLOAD16(src, (char*)wl + it * 6144 + wave * 1024);
    }
    __syncthreads();

    const int hh = (hn * 8 + r + SHIFT) % HHW;

    #pragma unroll
    for (int nt = 0; nt < 14; nt++) {
        const int px = nt * 16 + l16;
        const int wc = px >> 3, t7 = px & 7;
        const ushort* bp = x2 + ((size_t)(bh * 28 + wc) * 64 + r * 8 + t7) * 192;
        bf16x8 bq[6];
        #pragma unroll
        for (int k = 0; k < 6; k++) bq[k] = *(const bf16x8*)(bp + k * 32 + quad * 8);
        f32x4 acs[2];
        acs[0] = (f32x4){0.f, 0.f, 0.f, 0.f};
        acs[1] = (f32x4){0.f, 0.f, 0.f, 0.f};
        #pragma unroll
        for (int k = 0; k < 6; k++) {
            bf16x8 af0 = *(const bf16x8*)(wl + (((k * 4 + quad) * 12 + wave * 2 + 0) * 16 + l16) * 8);
            bf16x8 af1 = *(const bf16x8*)(wl + (((k * 4 + quad) * 12 + wave * 2 + 1) * 16 + l16) * 8);
            acs[0] = __builtin_amdgcn_mfma_f32_16x16x32_bf16(af0, bq[k], acs[0], 0, 0, 0);
            acs[1] = __builtin_amdgcn_mfma_f32_16x16x32_bf16(af1, bq[k], acs[1], 0, 0, 0);
        }
        const int ww = (px + SHIFT) % HHW;
        #pragma unroll
        for (int mm = 0; mm < 2; mm++) {
            const int o0 = wave * 32 + mm * 16 + quad * 4;
            float4 bb = *(const float4*)(bias + o0);
            float* dst = dout + (((size_t)(b * CCH + o0)) * HHW + hh) * HHW + ww;
            dst[0]                        = acs[mm][0] + bb.x;
            dst[(size_t)HHW * HHW]        = acs[mm][1] + bb.y;
            dst[2 * (size_t)HHW * HHW]    = acs[mm][2] + bb.z;
            dst[3 * (size_t)HHW * HHW]    = acs[mm][3] + bb.w;
        }
    }
}

extern "C" void kernel_launch(void* const* d_in, const int* in_sizes, int n_in,
                              void* d_out, int out_size, void* d_ws, size_t ws_size,
                              hipStream_t stream) {
    const float* x      = (const float*)d_in[0];
    const float* w_qkv  = (const float*)d_in[1];
    const float* b_qkv  = (const float*)d_in[2];
    const float* w_proj = (const float*)d_in[3];
    const float* b_proj = (const float*)d_in[4];
    float* out = (float*)d_out;
    ushort* ws = (ushort*)d_ws;

    ushort* X1 = (ushort*)d_out;       // 77 MB bf16 region inside d_out
    ushort* WQ = (ushort*)d_out + QN;  // qkv weight image (dead before out-writes)
    ushort* X2 = ws;                   // [win][t][192] bf16
    ushort* WP = ws + QN;              // proj weight image

    prep_w_qkv  <<<54, 256, 0, stream>>>(w_qkv, WQ);
    prep_x      <<<4 * 28 * 24, 256, 0, stream>>>(x, X1);
    qkv_attn_win<<<NWIN, 384, 0, stream>>>(X1, WQ, b_qkv, X2);
    prep_w_proj <<<18, 256, 0, stream>>>(w_proj, WP);
    gemm_proj   <<<4 * 28 * 8, 384, 0, stream>>>(X2, WP, b_proj, out);
}